// Round 1
// baseline (125.003 us; speedup 1.0000x reference)
//
#include <hip/hip_runtime.h>
#include <hip/hip_bf16.h>
#include <cstdint>

#define BATCH   32
#define NVARS   16
#define SAMPLES 4096
#define EDIM    128
#define NTOK    1016          // (4096-32)/4

typedef __bf16 bf8_t __attribute__((ext_vector_type(8)));
typedef float  f4_t  __attribute__((ext_vector_type(4)));

// ---------------------------------------------------------------------------
// prep_kernel: W_patch repack ONLY (encode is fused into the GEMM now).
// WtF[kb][g(8)][lane(64)][t(8)] = B[kbase(kb)+quad*8+t][g*16+l15]
//   (kbase=(4*dlt+(s&3))*128+(s>>2)*32, kb=s*8+dlt) -> a GEMM wave's
//   B-fragment group is one coalesced 1KB global load straight to VGPRs.
// ---------------------------------------------------------------------------
__global__ __launch_bounds__(256) void prep_kernel(
    const float* __restrict__ Wp, __hip_bfloat16* __restrict__ WtF)
{
  __shared__ float ls[32][132];
  int tid = threadIdx.x;
  int kb  = blockIdx.x;
  int s = kb >> 3, dlt = kb & 7;
  int kbase = (4 * dlt + (s & 3)) * 128 + (s >> 2) * 32;
#pragma unroll
  for (int r = 0; r < 16; ++r) {
    int idx = tid + r * 256;
    ls[idx >> 7][idx & 127] =
        Wp[(size_t)(kbase + (idx >> 7)) * EDIM + (idx & 127)];
  }
  __syncthreads();
  int g = tid >> 5, l5 = tid & 31;
#pragma unroll
  for (int h = 0; h < 2; ++h) {
    int lane = l5 + h * 32;
    int quad = lane >> 4, l15 = lane & 15;
    int n = g * 16 + l15;
    union { unsigned short u[8]; uint4 v; } pk;
#pragma unroll
    for (int t = 0; t < 8; ++t) {
      __hip_bfloat16 hh = __float2bfloat16(ls[quad * 8 + t][n]);
      pk.u[t] = *(unsigned short*)&hh;
    }
    *(uint4*)(WtF + (size_t)kb * 4096 + g * 512 + lane * 8) = pk.v;
  }
}

// ---------------------------------------------------------------------------
// Fused GEMM: encode (sample LSH) computed IN-KERNEL into the swizzled Apl
// layout, replacing the global enc round-trip (32 MB write + read) and the
// 512-block encode prep.  M=32512 N=128 K=4096, grid 256 (1 block/CU),
// 512 threads = 8 waves.  Intra-block K-split-2: waves 0-3 K[0,2048),
// waves 4-7 K[2048,4096); wave tile 64x64 (4x4 mfma 16x16x32).
//
// Encode: per group-plane (phase p, eblk e), 136 rows x 32 dims.  Thread
// owns fixed dim-quad h (4 dims), rows r0+{0,32,64,96}(+128 for wave 0);
// 5 units interleaved into the d-loop (d<5) so the VALU work rides in the
// MFMA shadow.  x staged transposed in LDS xT[4][136][20] f32 (pitch 20
// -> float4 reads hit banks {20r mod 32} = full stride-4 lattice,
// conflict-free).  W_sample cols for the thread's 4 dims live in 64 VGPRs,
// reloaded at the e-switch (ss==3).  Summation order (v ascending, f32)
// is IDENTICAL to the old prep -> bit-identical enc values.
// Swizzle consistency: write phys=((h>>1)+(u>>1))&3, read
// swzA=(quad+((t0+dlt+wm+l15)>>1))&3; the i*16 row term is even and
// =0 mod 4 after >>1, so read==write slot.  lgkmcnt(0) before each ss
// barrier publishes the ds_writes (replaces the old vmcnt-drain trick).
// T5: s_setprio(1) around the 16-MFMA cluster (encode-VALU vs MFMA role
// diversity now exists for the scheduler to arbitrate).
// ---------------------------------------------------------------------------
__global__ __launch_bounds__(512, 2) void gemm_kernel(
    const float* __restrict__ x,
    const float* __restrict__ Ws,
    const float* __restrict__ bs,
    const __hip_bfloat16* __restrict__ WtF,
    const float* __restrict__ bp,
    float* __restrict__ out)
{
  __shared__ __align__(16) __hip_bfloat16 Apl[2][2][4608];  // 36 KB
  __shared__ __align__(16) float xT[4][136][20];            // 42.5 KB

  int tid  = threadIdx.x;
  int lane = tid & 63;
  int wv   = tid >> 6;               // 0..7
  int g    = wv >> 2;                // K-half
  int wq   = wv & 3;                 // quadrant of 128x128
  int b    = blockIdx.x >> 3;
  int t0   = (blockIdx.x & 7) << 7;
  int wm   = (wq >> 1) << 6;         // 0/64
  int wn   = (wq & 1) << 6;          // 0/64
  int quad = lane >> 4;
  int l15  = lane & 15;

  const __hip_bfloat16* bg = WtF + (size_t)(wn >> 4) * 512 + lane * 8;

  f4_t acc[4][4];
  f4_t zero = {0.f, 0.f, 0.f, 0.f};
#pragma unroll
  for (int i = 0; i < 4; ++i)
#pragma unroll
    for (int j = 0; j < 4; ++j) acc[i][j] = zero;

  // ---- stage x[b][v][4t0 .. 4t0+543] transposed into xT (clamped) ----
  {
    int v = tid >> 5, l5 = tid & 31;
    const float* xb = x + ((size_t)b * NVARS + v) * SAMPLES;
    int sb = t0 << 2;
#pragma unroll
    for (int j = 0; j < 17; ++j) {
      int i = l5 + j * 32;           // 0..543
      int s = sb + i; s = s > (SAMPLES - 1) ? (SAMPLES - 1) : s;
      xT[i & 3][i >> 2][v] = xb[s];
    }
  }

  // ---- W_sample columns for this thread's dim-quad (reload at e-switch) --
  float w[NVARS][4];
  float bz[4];
  auto loadW = [&](int e) {
    int d0 = e * 32 + (tid & 7) * 4;
#pragma unroll
    for (int v = 0; v < NVARS; ++v)
      *(float4*)&w[v][0] = *(const float4*)(Ws + v * EDIM + d0);
    *(float4*)&bz[0] = *(const float4*)(bs + d0);
  };
  loadW(g * 2);

  // ---- one encode unit: 4 dims x 1 row -> swizzled Apl slot ----
  auto encU = [&](int Pg, int buf, int k) {
    int gt = tid & 255;                       // group-local thread
    if (k == 4 && gt >= 64) return;           // tail rows: wave 0 of group
    int p  = Pg & 3;
    int r0 = gt >> 3;
    int r  = (k < 4) ? (r0 + k * 32) : (128 + r0);   // 0..135
    int h  = tid & 7;
    const float* xrow = &xT[p][r][0];
    float xr[NVARS];
    *(float4*)&xr[0]  = *(const float4*)(xrow + 0);
    *(float4*)&xr[4]  = *(const float4*)(xrow + 4);
    *(float4*)&xr[8]  = *(const float4*)(xrow + 8);
    *(float4*)&xr[12] = *(const float4*)(xrow + 12);
    float a0 = bz[0], a1 = bz[1], a2 = bz[2], a3 = bz[3];
#pragma unroll
    for (int v = 0; v < NVARS; ++v) {
      a0 += xr[v] * w[v][0]; a1 += xr[v] * w[v][1];
      a2 += xr[v] * w[v][2]; a3 += xr[v] * w[v][3];
    }
    int u    = t0 + r;
    int phys = ((h >> 1) + (u >> 1)) & 3;
    union { unsigned short us[4]; uint2 q; } pk;
    pk.us[0] = (unsigned short)(__float_as_uint(floorf(a0)) >> 16);
    pk.us[1] = (unsigned short)(__float_as_uint(floorf(a1)) >> 16);
    pk.us[2] = (unsigned short)(__float_as_uint(floorf(a2)) >> 16);
    pk.us[3] = (unsigned short)(__float_as_uint(floorf(a3)) >> 16);
    *(uint2*)(&Apl[g][buf][0] + (size_t)r * 32 + phys * 8 + (h & 1) * 4) =
        pk.q;
  };

  auto loadB = [&](int kb, uint4* d) {
#pragma unroll
    for (int j = 0; j < 4; ++j)
      d[j] = *(const uint4*)(bg + (size_t)kb * 4096 + j * 512);
  };

  auto compute = [&](int abuf, int dlt, const uint4* bq_) {
    const bf8_t* pA = (const bf8_t*)&Apl[g][abuf][0];
    int swzA = (quad + ((t0 + dlt + wm + l15) >> 1)) & 3;
    bf8_t af[4];
#pragma unroll
    for (int i = 0; i < 4; ++i)
      af[i] = pA[(dlt + wm + i * 16 + l15) * 4 + swzA];
    __builtin_amdgcn_s_setprio(1);
#pragma unroll
    for (int mi = 0; mi < 4; ++mi)
#pragma unroll
      for (int ni = 0; ni < 4; ++ni)
        acc[mi][ni] = __builtin_amdgcn_mfma_f32_16x16x32_bf16(
            af[mi], __builtin_bit_cast(bf8_t, bq_[ni]), acc[mi][ni], 0, 0, 0);
    __builtin_amdgcn_s_setprio(0);
  };

  // ---- prologue: xT ready, encode plane 0 into buf 0, first B loads ----
  __syncthreads();
#pragma unroll
  for (int k = 0; k < 5; ++k) encU(g * 8, 0, k);
  asm volatile("s_waitcnt lgkmcnt(0)" ::: "memory");
  asm volatile("s_barrier" ::: "memory");

  uint4 bq[2][4];
  loadB(g * 64, bq[0]);
  loadB(g * 64 + 1, bq[1]);

  for (int ss = 0; ss < 8; ++ss) {           // group-local supersteps
    if (ss == 3) loadW(g * 2 + 1);           // e-switch for planes 4..7
#pragma unroll
    for (int d = 0; d < 8; ++d) {
      int kl = ss * 8 + d;                   // group-local kb 0..63
      compute(ss & 1, d, bq[d & 1]);
      if (kl < 62) loadB(g * 64 + kl + 2, bq[d & 1]);
      if (ss < 7 && d < 5) encU(g * 8 + ss + 1, (ss + 1) & 1, d);
    }
    asm volatile("s_waitcnt lgkmcnt(0)" ::: "memory");
    asm volatile("s_barrier" ::: "memory");
  }

  // ---- K-half reduction (group1 -> group0 via LDS) + fused epilogue ----
  // stride-17 float rows: 17 coprime to 32 -> conflict-free LDS access.
  float* rb = (float*)&Apl[0][0][0];         // 4352 floats = 17 KB per round
  int widx = (wq * 64 + lane) * 17;
  float bias[4];
#pragma unroll
  for (int ni = 0; ni < 4; ++ni) bias[ni] = bp[wn + ni * 16 + l15];

#pragma unroll
  for (int mi = 0; mi < 4; ++mi) {
    __syncthreads();
    if (g == 1) {
#pragma unroll
      for (int ni = 0; ni < 4; ++ni)
#pragma unroll
        for (int r = 0; r < 4; ++r)
          rb[widx + ni * 4 + r] = acc[mi][ni][r];
    }
    __syncthreads();
    if (g == 0) {
#pragma unroll
      for (int ni = 0; ni < 4; ++ni)
#pragma unroll
        for (int r = 0; r < 4; ++r) {
          int t = t0 + wm + mi * 16 + quad * 4 + r;
          if (t < NTOK) {
            int n = wn + ni * 16 + l15;
            out[((size_t)b * NTOK + t) * EDIM + n] =
                floorf(acc[mi][ni][r] + rb[widx + ni * 4 + r] + bias[ni]);
          }
        }
    }
  }
}

// ---------------------------------------------------------------------------
extern "C" void kernel_launch(void* const* d_in, const int* in_sizes, int n_in,
                              void* d_out, int out_size, void* d_ws, size_t ws_size,
                              hipStream_t stream) {
  const float* x  = (const float*)d_in[0];
  const float* Ws = (const float*)d_in[1];
  const float* bs = (const float*)d_in[2];
  const float* Wp = (const float*)d_in[3];
  const float* bp = (const float*)d_in[4];
  float* out = (float*)d_out;

  __hip_bfloat16* WtF = (__hip_bfloat16*)d_ws;   // 1 MB fragment-major B

  prep_kernel<<<128, 256, 0, stream>>>(Wp, WtF);
  gemm_kernel<<<BATCH * 8, 512, 0, stream>>>(x, Ws, bs, WtF, bp, out);
}